// Round 11
// baseline (281.619 us; speedup 1.0000x reference)
//
#include <hip/hip_runtime.h>

// VQ-VAE vector quantization, MI355X gfx950.
// B=16, C=64, H=W=64 -> N=65536 pixels; K=1024 codes, dim 64.
// NUMERICS (DO NOT CHANGE — r7 passed absmax 0.0 with exactly this):
//   nz/ne: numpy pairwise sum, 8-accumulator unroll, products rounded
//          separately (no fma contraction);
//   dot:   single ascending fp32 fma chain per (pixel,code);
//   d = fl( fl(nz - fl(2*dot)) + ne ); strict-< ascending-k tie-break.
//   ~135 pixels are decided by quantized ties.
//
// Perf history:
//   r7 161 | r8 185 | r9 137 | r12 242 | r13 137 | r14 1244 | r15 135
//   r16 hybrid LDS+SGPR argmin 133, total 196 (BEST baseline).
//   r17/r18/r20 finalize restructures: ALL regressed (209/218/204) while
//       argmin sat at its 8-variant floor (131-140). Diagnosis: ANY separate
//       finalize kernel must re-read z (16.7MB) + cmin/cidx (4MB) cold;
//       the needed z values were in argmin's registers one dispatch earlier.
// r21: DELETE the finalize kernel. Split-K handoff via packed u64 atomicMin
//   per pixel: (bits(best)<<32)|bi — d>0 so float bits are monotonic as
//   uint; idx in low word makes equal-d ties pick lowest k = reference
//   first-min tie-break, bit-exact. Per pixel column, a device-scope
//   counter finds the 8th-finishing chunk-block; it finalizes its 512
//   pixels FROM ITS OWN zr REGISTERS: emb float4 gather -> z_q + indices,
//   loss chain d = e - zr[c] ascending (same bits as r16's e - zv).
//   chunk = blockIdx.x so a column's 8 blocks dispatch consecutively and
//   tails overlap other columns' compute. Tiny init kernel re-poisons
//   packed/counters (graph-replay safe). Main loop: r16 VERBATIM.
#define N_PIX   65536
#define CDIM    64
#define KCODES  1024
#define HWSZ    4096          // H*W
#define KCHUNK  128           // codes per argmin block
#define NCHUNK  8             // KCODES / KCHUNK
#define TPB     256
#define PXT     2             // pixels per thread; 128*256*2 == N_PIX exactly
#define GRIDX   (N_PIX / (TPB * PXT))   // 128 pixel columns

// workspace layout (float-element offsets)
#define OFF_PACKED  0         // 65536 u64 (131072 f32): per-pixel (dbits,idx)
#define OFF_COLCTR  131072    // 128 u32: per-column chunk-done counters
#define OFF_CTR2    131200    // 1 u32: finishing-block counter (loss emit)
#define OFF_LOSS    131204    // 1 f32: SSE accumulator

// output layout (float-element offsets): z_q | indices | loss
#define OUT_IDX  (N_PIX * CDIM)         // 4194304
#define OUT_LOSS (OUT_IDX + N_PIX)      // 4259840

typedef __attribute__((ext_vector_type(16))) float f32x16;

// exact numpy pairwise ||.||^2 for pixel registers — EXACT r9-verified form.
__device__ __forceinline__ float np_nz(const float* zr) {
    float r0 = zr[0]*zr[0], r1 = zr[1]*zr[1], r2 = zr[2]*zr[2], r3 = zr[3]*zr[3];
    float r4 = zr[4]*zr[4], r5 = zr[5]*zr[5], r6 = zr[6]*zr[6], r7 = zr[7]*zr[7];
#pragma unroll
    for (int i = 8; i < CDIM; i += 8) {
        r0 = r0 + zr[i+0]*zr[i+0]; r1 = r1 + zr[i+1]*zr[i+1];
        r2 = r2 + zr[i+2]*zr[i+2]; r3 = r3 + zr[i+3]*zr[i+3];
        r4 = r4 + zr[i+4]*zr[i+4]; r5 = r5 + zr[i+5]*zr[i+5];
        r6 = r6 + zr[i+6]*zr[i+6]; r7 = r7 + zr[i+7]*zr[i+7];
    }
    return ((r0 + r1) + (r2 + r3)) + ((r4 + r5) + (r6 + r7));
}

// ---------------- Kernel 0: workspace re-poison (graph-replay safe) ---------
__global__ void vq_init(float* __restrict__ ws) {
    const int i = blockIdx.x * blockDim.x + threadIdx.x;      // 65536 threads
    ((unsigned long long*)ws)[i] = ~0ull;                     // packed = +inf
    if (i < GRIDX) ((unsigned*)(ws + OFF_COLCTR))[i] = 0u;
    if (i == 0) {
        ((unsigned*)(ws + OFF_CTR2))[0] = 0u;
        ws[OFF_LOSS] = 0.0f;
    }
}

// ---------------- Kernel A: argmin + fused per-column finalize --------------
// grid = (NCHUNK, GRIDX): blockIdx.x = chunk (consecutive dispatch within a
// column), blockIdx.y = pixel column. block = TPB.
__global__ __launch_bounds__(TPB, 3) void vq_argmin(const float* __restrict__ z,
                                                    const float* __restrict__ emb,
                                                    float* __restrict__ out,
                                                    float* __restrict__ ws) {
#pragma clang fp contract(off)
    __shared__ float se[KCHUNK * CDIM];   // 32 KB
    __shared__ float sn[KCHUNK];

    const int chunk = blockIdx.x;
    const int k0 = chunk * KCHUNK;

    // stage this chunk's embedding rows (coalesced float4)
    const float4* esrc = (const float4*)(emb + (size_t)k0 * CDIM);
    float4* edst = (float4*)se;
    for (int i = threadIdx.x; i < KCHUNK * CDIM / 4; i += TPB) edst[i] = esrc[i];
    __syncthreads();
    // fused prep: ||e_k||^2 from the bit-exact staged copy (validated r12-r16).
    // Known cost: 32-way bank conflict here, ~2M cycles (~3 µs). Accepted.
    if (threadIdx.x < KCHUNK) {
        const float* e = se + threadIdx.x * CDIM;
        float r0 = e[0]*e[0], r1 = e[1]*e[1], r2 = e[2]*e[2], r3 = e[3]*e[3];
        float r4 = e[4]*e[4], r5 = e[5]*e[5], r6 = e[6]*e[6], r7 = e[7]*e[7];
#pragma unroll
        for (int i = 8; i < CDIM; i += 8) {
            r0 = r0 + e[i+0]*e[i+0]; r1 = r1 + e[i+1]*e[i+1];
            r2 = r2 + e[i+2]*e[i+2]; r3 = r3 + e[i+3]*e[i+3];
            r4 = r4 + e[i+4]*e[i+4]; r5 = r5 + e[i+5]*e[i+5];
            r6 = r6 + e[i+6]*e[i+6]; r7 = r7 + e[i+7]*e[i+7];
        }
        sn[threadIdx.x] = ((r0 + r1) + (r2 + r3)) + ((r4 + r5) + (r6 + r7));
    }
    __syncthreads();

    // two pixels per thread, lane-coalesced; no tail (128*256*2 == N_PIX)
    const int p0 = blockIdx.y * (TPB * PXT) + threadIdx.x;
    const int p1 = p0 + TPB;
    const int b0 = p0 >> 12, hw0 = p0 & (HWSZ - 1);
    const int b1 = p1 >> 12, hw1 = p1 & (HWSZ - 1);

    float zr0[CDIM], zr1[CDIM];
    {
        const float* zp0 = z + ((size_t)(b0 * CDIM) << 12) + hw0;
        const float* zp1 = z + ((size_t)(b1 * CDIM) << 12) + hw1;
#pragma unroll
        for (int c = 0; c < CDIM; ++c) {
            zr0[c] = zp0[(size_t)c << 12];
            zr1[c] = zp1[(size_t)c << 12];
        }
    }
    const float nz0 = np_nz(zr0);
    const float nz1 = np_nz(zr1);

    float best0 = 3.4e38f, best1 = 3.4e38f;
    int   bi0   = k0,      bi1   = k0;

    for (int kk = 0; kk < KCHUNK; kk += 2) {
        // --- issue SGPR stream for code kk+1 (erow + 0x100..0x1c0) ---------
        const float* erow = emb + (size_t)(k0 + kk) * CDIM;
        f32x16 ec0, ec1, ec2, ec3;
        asm volatile(
            "s_load_dwordx16 %0, %4, 0x100\n\t"
            "s_load_dwordx16 %1, %4, 0x140\n\t"
            "s_load_dwordx16 %2, %4, 0x180\n\t"
            "s_load_dwordx16 %3, %4, 0x1c0"
            : "=s"(ec0), "=s"(ec1), "=s"(ec2), "=s"(ec3)
            : "s"(erow));

        // --- LDS phase: code kk for both pixels (r9's exact chains) --------
        const float4* e0 = (const float4*)(se + kk * CDIM);
        float a00 = 0.f, a01 = 0.f, a10 = 0.f, a11 = 0.f;
#pragma unroll
        for (int j = 0; j < 16; ++j) {
            float4 v0 = e0[j];                 // uniform addr -> LDS broadcast
            a00 = fmaf(zr0[4*j+0], v0.x, a00);
            a00 = fmaf(zr0[4*j+1], v0.y, a00);
            a00 = fmaf(zr0[4*j+2], v0.z, a00);
            a00 = fmaf(zr0[4*j+3], v0.w, a00);
            a10 = fmaf(zr1[4*j+0], v0.x, a10);
            a10 = fmaf(zr1[4*j+1], v0.y, a10);
            a10 = fmaf(zr1[4*j+2], v0.z, a10);
            a10 = fmaf(zr1[4*j+3], v0.w, a10);
        }

        // --- wait: pinned AFTER the LDS phase (produces a00,a10) and BEFORE
        //     the SGPR phase (consumes ec0..ec3 as this asm's outputs) -------
        asm volatile("s_waitcnt lgkmcnt(0)"
                     : "+s"(ec0), "+s"(ec1), "+s"(ec2), "+s"(ec3),
                       "+v"(a00), "+v"(a10));

        // --- SGPR phase: code kk+1 for both pixels (r15's exact chains) ----
#pragma unroll
        for (int j = 0; j < 16; ++j) {
            a01 = fmaf(zr0[j], ec0[j], a01);   // v_fma: VGPR,SGPR,VGPR
            a11 = fmaf(zr1[j], ec0[j], a11);
        }
#pragma unroll
        for (int j = 0; j < 16; ++j) {
            a01 = fmaf(zr0[16+j], ec1[j], a01);
            a11 = fmaf(zr1[16+j], ec1[j], a11);
        }
#pragma unroll
        for (int j = 0; j < 16; ++j) {
            a01 = fmaf(zr0[32+j], ec2[j], a01);
            a11 = fmaf(zr1[32+j], ec2[j], a11);
        }
#pragma unroll
        for (int j = 0; j < 16; ++j) {
            a01 = fmaf(zr0[48+j], ec3[j], a01);
            a11 = fmaf(zr1[48+j], ec3[j], a11);
        }

        // d and argmin — exact r9 expression shapes and update order
        float d00 = (nz0 - 2.0f * a00) + sn[kk];
        float d01 = (nz0 - 2.0f * a01) + sn[kk + 1];
        float d10 = (nz1 - 2.0f * a10) + sn[kk];
        float d11 = (nz1 - 2.0f * a11) + sn[kk + 1];
        if (d00 < best0) { best0 = d00; bi0 = k0 + kk; }
        if (d01 < best0) { best0 = d01; bi0 = k0 + kk + 1; }
        if (d10 < best1) { best1 = d10; bi1 = k0 + kk; }
        if (d11 < best1) { best1 = d11; bi1 = k0 + kk + 1; }
    }

    // --- split-K handoff: packed (dbits<<32)|idx, device-scope atomicMin ----
    // d > 0 on this data -> positive-float bits monotonic as u32; idx in low
    // word -> equal-d ties pick lowest k == reference first-min tie-break.
    unsigned long long* packed = (unsigned long long*)ws;
    const unsigned long long pk0 =
        ((unsigned long long)__float_as_uint(best0) << 32) | (unsigned)bi0;
    const unsigned long long pk1 =
        ((unsigned long long)__float_as_uint(best1) << 32) | (unsigned)bi1;
    atomicMin(packed + p0, pk0);
    atomicMin(packed + p1, pk1);
    __threadfence();                           // mins visible before counter

    __shared__ int lastf;
    if (threadIdx.x == 0) {
        unsigned old = atomicAdd((unsigned*)(ws + OFF_COLCTR) + blockIdx.y, 1u);
        lastf = (old == NCHUNK - 1);
    }
    __syncthreads();
    if (!lastf) return;

    // --- fused finalize: this block is 8th/8 for its 512 pixels. zr0/zr1
    //     are STILL IN REGISTERS — no z re-read. Coherent atomic reads of
    //     the packed minima; emb float4 gather; z_q + indices + loss.
    const unsigned long long q0 = atomicAdd(packed + p0, 0ull);
    const unsigned long long q1 = atomicAdd(packed + p1, 0ull);
    const int wbi0 = (int)(q0 & 0xFFFFFFFFull);
    const int wbi1 = (int)(q1 & 0xFFFFFFFFull);
    out[OUT_IDX + p0] = (float)wbi0;           // coalesced (lanes consecutive)
    out[OUT_IDX + p1] = (float)wbi1;

    float ls = 0.0f;
    {   // pixel 0: ascending single chain, d = e - zr (same bits as e - zv)
        const float4* ev = (const float4*)(emb + (size_t)wbi0 * CDIM);
        float* zq = out + ((size_t)(b0 * CDIM) << 12) + hw0;
        float l = 0.0f;
#pragma unroll
        for (int j = 0; j < 16; ++j) {
            float4 v = ev[j];                  // gather: row hits L1/L2
            float d0 = v.x - zr0[4*j+0]; l = fmaf(d0, d0, l);
            float d1 = v.y - zr0[4*j+1]; l = fmaf(d1, d1, l);
            float d2 = v.z - zr0[4*j+2]; l = fmaf(d2, d2, l);
            float d3 = v.w - zr0[4*j+3]; l = fmaf(d3, d3, l);
            zq[(size_t)(4*j+0) << 12] = v.x;   // coalesced strided stores
            zq[(size_t)(4*j+1) << 12] = v.y;
            zq[(size_t)(4*j+2) << 12] = v.z;
            zq[(size_t)(4*j+3) << 12] = v.w;
        }
        ls += l;
    }
    {   // pixel 1
        const float4* ev = (const float4*)(emb + (size_t)wbi1 * CDIM);
        float* zq = out + ((size_t)(b1 * CDIM) << 12) + hw1;
        float l = 0.0f;
#pragma unroll
        for (int j = 0; j < 16; ++j) {
            float4 v = ev[j];
            float d0 = v.x - zr1[4*j+0]; l = fmaf(d0, d0, l);
            float d1 = v.y - zr1[4*j+1]; l = fmaf(d1, d1, l);
            float d2 = v.z - zr1[4*j+2]; l = fmaf(d2, d2, l);
            float d3 = v.w - zr1[4*j+3]; l = fmaf(d3, d3, l);
            zq[(size_t)(4*j+0) << 12] = v.x;
            zq[(size_t)(4*j+1) << 12] = v.y;
            zq[(size_t)(4*j+2) << 12] = v.z;
            zq[(size_t)(4*j+3) << 12] = v.w;
        }
        ls += l;
    }

    // block reduction -> one atomic; last finishing block scales + emits loss
#pragma unroll
    for (int off = 32; off > 0; off >>= 1) ls += __shfl_down(ls, off);
    __shared__ float wsum[TPB / 64];
    if ((threadIdx.x & 63) == 0) wsum[threadIdx.x >> 6] = ls;
    __syncthreads();
    if (threadIdx.x == 0) {
        float s = (wsum[0] + wsum[1]) + (wsum[2] + wsum[3]);
        float* loss_acc = ws + OFF_LOSS;
        atomicAdd(loss_acc, s);
        __threadfence();                               // add visible before count
        unsigned* ctr2 = (unsigned*)(ws + OFF_CTR2);
        unsigned old = atomicAdd(ctr2, 1u);
        if (old == (unsigned)(GRIDX - 1)) {            // last of 128 finishers
            __threadfence();
            float total = atomicAdd(loss_acc, 0.0f);   // coherent read
            // vq_loss + beta*commitment = (1+0.25) * SSE / numel(z)
            out[OUT_LOSS] = total * (1.25f / (float)(N_PIX * CDIM));
        }
    }
}

extern "C" void kernel_launch(void* const* d_in, const int* in_sizes, int n_in,
                              void* d_out, int out_size, void* d_ws, size_t ws_size,
                              hipStream_t stream) {
    const float* z   = (const float*)d_in[0];
    const float* emb = (const float*)d_in[1];
    float* ws   = (float*)d_ws;
    float* out  = (float*)d_out;

    vq_init<<<dim3(N_PIX / TPB), dim3(TPB), 0, stream>>>(ws);
    vq_argmin<<<dim3(NCHUNK, GRIDX), dim3(TPB), 0, stream>>>(z, emb, out, ws);
}

// Round 12
// 209.360 us; speedup vs baseline: 1.3451x; 1.3451x over previous
//
#include <hip/hip_runtime.h>

// VQ-VAE vector quantization, MI355X gfx950.
// B=16, C=64, H=W=64 -> N=65536 pixels; K=1024 codes, dim 64.
// NUMERICS (DO NOT CHANGE — r7 passed absmax 0.0 with exactly this):
//   nz/ne: numpy pairwise sum, 8-accumulator unroll, products rounded
//          separately (no fma contraction);
//   dot:   single ascending fp32 fma chain per (pixel,code);
//   d = fl( fl(nz - fl(2*dot)) + ne ); strict-< ascending-k tie-break.
//   ~135 pixels are decided by quantized ties.
//
// Perf history:
//   r7 161 | r8 185 | r9 137 | r12 242 | r13 137 | r14 1244 | r15 135
//   r16 hybrid LDS+SGPR argmin 133, total 196 (BEST baseline).
//   r17 finalize FB=128: 209 (wave count unchanged — 4 waves/CU).
//   r18 4-way wave split: 218 (4x segments/instr + sync).
//   r20 2-way wave-half split: 204 (8 waves/CU BUT 2 segments/instr —
//       coalescing loss ate the TLP gain).
//   r21 atomic-fused single kernel: 282 (524K u64 atomicMin + per-thread
//       fences taxed every block; HBM fell to 83 GB/s). Atomics on the
//       hot path are structurally wrong. REVERTED.
// r22: the one untested cell — more waves AND intact coalescing.
//   finalize block=256 = 128 px x 2 channel-halves with h = tid>>7:
//   wave0 = ch0-31 px0-63, wave1 = ch0-31 px64-127, waves2-3 = ch32-63.
//   Every wave: 64 CONSECUTIVE pixels, one channel range -> every z/zq
//   instruction is ONE 256B segment (r16-identical), threads 2x shorter,
//   grid 512 blocks -> 8 waves/CU (2x r16). Chunk-reduce duplicated per
//   half (no LDS/sync); 32-ch loss chains (r20 bit-validated grouping).
//   argmin: r16 VERBATIM.
#define N_PIX   65536
#define CDIM    64
#define KCODES  1024
#define HWSZ    4096          // H*W
#define KCHUNK  128           // codes per argmin block
#define NCHUNK  8             // KCODES / KCHUNK
#define TPB     256
#define PXT     2             // pixels per thread; 128*256*2 == N_PIX exactly
#define GRIDX   (N_PIX / (TPB * PXT))   // 128
#define FPPB    128           // finalize pixels per block (256 thr, 2 thr/px)

// workspace layout (float-element offsets) — r16 layout
#define OFF_CTR  0            // 1 u32: finalize done-counter
#define OFF_MIN  1024         // 65536*8 f32: per-chunk min score
#define OFF_IDX  525312       // 65536*8 i32: per-chunk argmin
#define OFF_LOSS 1049600      // 1 f32: SSE accumulator

// output layout (float-element offsets): z_q | indices | loss
#define OUT_IDX  (N_PIX * CDIM)         // 4194304
#define OUT_LOSS (OUT_IDX + N_PIX)      // 4259840

typedef __attribute__((ext_vector_type(16))) float f32x16;

// exact numpy pairwise ||.||^2 for pixel registers — EXACT r9-verified form.
__device__ __forceinline__ float np_nz(const float* zr) {
    float r0 = zr[0]*zr[0], r1 = zr[1]*zr[1], r2 = zr[2]*zr[2], r3 = zr[3]*zr[3];
    float r4 = zr[4]*zr[4], r5 = zr[5]*zr[5], r6 = zr[6]*zr[6], r7 = zr[7]*zr[7];
#pragma unroll
    for (int i = 8; i < CDIM; i += 8) {
        r0 = r0 + zr[i+0]*zr[i+0]; r1 = r1 + zr[i+1]*zr[i+1];
        r2 = r2 + zr[i+2]*zr[i+2]; r3 = r3 + zr[i+3]*zr[i+3];
        r4 = r4 + zr[i+4]*zr[i+4]; r5 = r5 + zr[i+5]*zr[i+5];
        r6 = r6 + zr[i+6]*zr[i+6]; r7 = r7 + zr[i+7]*zr[i+7];
    }
    return ((r0 + r1) + (r2 + r3)) + ((r4 + r5) + (r6 + r7));
}

// ---------------- Kernel A: split-K argmin, hybrid LDS+SGPR (r16 verbatim) --
// grid = (GRIDX, NCHUNK); block = TPB.
__global__ __launch_bounds__(TPB, 3) void vq_argmin(const float* __restrict__ z,
                                                    const float* __restrict__ emb,
                                                    float* __restrict__ cmin,
                                                    int* __restrict__ cidx,
                                                    float* __restrict__ ws) {
#pragma clang fp contract(off)
    __shared__ float se[KCHUNK * CDIM];   // 32 KB
    __shared__ float sn[KCHUNK];

    const int chunk = blockIdx.y;
    const int k0 = chunk * KCHUNK;

    if ((blockIdx.x | blockIdx.y) == 0 && threadIdx.x == 0) {
        ws[OFF_LOSS] = 0.0f;                       // stream-ordered before finalize
        ((unsigned*)ws)[OFF_CTR] = 0u;             // graph-replay / re-poison safe
    }

    // stage this chunk's embedding rows (coalesced float4)
    const float4* esrc = (const float4*)(emb + (size_t)k0 * CDIM);
    float4* edst = (float4*)se;
    for (int i = threadIdx.x; i < KCHUNK * CDIM / 4; i += TPB) edst[i] = esrc[i];
    __syncthreads();
    // fused prep: ||e_k||^2 from the bit-exact staged copy (validated r12-r16).
    // Known cost: 32-way bank conflict here, ~2M cycles (~3 µs). Accepted.
    if (threadIdx.x < KCHUNK) {
        const float* e = se + threadIdx.x * CDIM;
        float r0 = e[0]*e[0], r1 = e[1]*e[1], r2 = e[2]*e[2], r3 = e[3]*e[3];
        float r4 = e[4]*e[4], r5 = e[5]*e[5], r6 = e[6]*e[6], r7 = e[7]*e[7];
#pragma unroll
        for (int i = 8; i < CDIM; i += 8) {
            r0 = r0 + e[i+0]*e[i+0]; r1 = r1 + e[i+1]*e[i+1];
            r2 = r2 + e[i+2]*e[i+2]; r3 = r3 + e[i+3]*e[i+3];
            r4 = r4 + e[i+4]*e[i+4]; r5 = r5 + e[i+5]*e[i+5];
            r6 = r6 + e[i+6]*e[i+6]; r7 = r7 + e[i+7]*e[i+7];
        }
        sn[threadIdx.x] = ((r0 + r1) + (r2 + r3)) + ((r4 + r5) + (r6 + r7));
    }
    __syncthreads();

    // two pixels per thread, lane-coalesced; no tail (128*256*2 == N_PIX)
    const int p0 = blockIdx.x * (TPB * PXT) + threadIdx.x;
    const int p1 = p0 + TPB;

    float zr0[CDIM], zr1[CDIM];
    {
        const int b0  = p0 >> 12, hw0 = p0 & (HWSZ - 1);
        const int b1  = p1 >> 12, hw1 = p1 & (HWSZ - 1);
        const float* zp0 = z + ((size_t)(b0 * CDIM) << 12) + hw0;
        const float* zp1 = z + ((size_t)(b1 * CDIM) << 12) + hw1;
#pragma unroll
        for (int c = 0; c < CDIM; ++c) {
            zr0[c] = zp0[(size_t)c << 12];
            zr1[c] = zp1[(size_t)c << 12];
        }
    }
    const float nz0 = np_nz(zr0);
    const float nz1 = np_nz(zr1);

    float best0 = 3.4e38f, best1 = 3.4e38f;
    int   bi0   = k0,      bi1   = k0;

    for (int kk = 0; kk < KCHUNK; kk += 2) {
        // --- issue SGPR stream for code kk+1 (erow + 0x100..0x1c0) ---------
        const float* erow = emb + (size_t)(k0 + kk) * CDIM;
        f32x16 ec0, ec1, ec2, ec3;
        asm volatile(
            "s_load_dwordx16 %0, %4, 0x100\n\t"
            "s_load_dwordx16 %1, %4, 0x140\n\t"
            "s_load_dwordx16 %2, %4, 0x180\n\t"
            "s_load_dwordx16 %3, %4, 0x1c0"
            : "=s"(ec0), "=s"(ec1), "=s"(ec2), "=s"(ec3)
            : "s"(erow));

        // --- LDS phase: code kk for both pixels (r9's exact chains) --------
        const float4* e0 = (const float4*)(se + kk * CDIM);
        float a00 = 0.f, a01 = 0.f, a10 = 0.f, a11 = 0.f;
#pragma unroll
        for (int j = 0; j < 16; ++j) {
            float4 v0 = e0[j];                 // uniform addr -> LDS broadcast
            a00 = fmaf(zr0[4*j+0], v0.x, a00);
            a00 = fmaf(zr0[4*j+1], v0.y, a00);
            a00 = fmaf(zr0[4*j+2], v0.z, a00);
            a00 = fmaf(zr0[4*j+3], v0.w, a00);
            a10 = fmaf(zr1[4*j+0], v0.x, a10);
            a10 = fmaf(zr1[4*j+1], v0.y, a10);
            a10 = fmaf(zr1[4*j+2], v0.z, a10);
            a10 = fmaf(zr1[4*j+3], v0.w, a10);
        }

        // --- wait: pinned AFTER the LDS phase (produces a00,a10) and BEFORE
        //     the SGPR phase (consumes ec0..ec3 as this asm's outputs) -------
        asm volatile("s_waitcnt lgkmcnt(0)"
                     : "+s"(ec0), "+s"(ec1), "+s"(ec2), "+s"(ec3),
                       "+v"(a00), "+v"(a10));

        // --- SGPR phase: code kk+1 for both pixels (r15's exact chains) ----
#pragma unroll
        for (int j = 0; j < 16; ++j) {
            a01 = fmaf(zr0[j], ec0[j], a01);   // v_fma: VGPR,SGPR,VGPR
            a11 = fmaf(zr1[j], ec0[j], a11);
        }
#pragma unroll
        for (int j = 0; j < 16; ++j) {
            a01 = fmaf(zr0[16+j], ec1[j], a01);
            a11 = fmaf(zr1[16+j], ec1[j], a11);
        }
#pragma unroll
        for (int j = 0; j < 16; ++j) {
            a01 = fmaf(zr0[32+j], ec2[j], a01);
            a11 = fmaf(zr1[32+j], ec2[j], a11);
        }
#pragma unroll
        for (int j = 0; j < 16; ++j) {
            a01 = fmaf(zr0[48+j], ec3[j], a01);
            a11 = fmaf(zr1[48+j], ec3[j], a11);
        }

        // d and argmin — exact r9 expression shapes and update order
        float d00 = (nz0 - 2.0f * a00) + sn[kk];
        float d01 = (nz0 - 2.0f * a01) + sn[kk + 1];
        float d10 = (nz1 - 2.0f * a10) + sn[kk];
        float d11 = (nz1 - 2.0f * a11) + sn[kk + 1];
        if (d00 < best0) { best0 = d00; bi0 = k0 + kk; }
        if (d01 < best0) { best0 = d01; bi0 = k0 + kk + 1; }
        if (d10 < best1) { best1 = d10; bi1 = k0 + kk; }
        if (d11 < best1) { best1 = d11; bi1 = k0 + kk + 1; }
    }
    cmin[(p0 << 3) + chunk] = best0;
    cidx[(p0 << 3) + chunk] = bi0;
    cmin[(p1 << 3) + chunk] = best1;
    cidx[(p1 << 3) + chunk] = bi1;
}

// ---------------- Kernel B: reduce chunks, gather z_q, loss + emit ----------
// 2 threads/pixel with WAVE-ALIGNED halves: h = tid>>7 (not lane>>5), so
// wave0 = ch0-31 of px 0-63, wave1 = ch0-31 of px 64-127, waves 2-3 = ch32-63.
// Every wave: 64 consecutive pixels, one channel range -> each z/zq access
// is ONE 256B segment (r16-identical coalescing). grid = 512 blocks ->
// 2048 waves = 8 waves/CU (2x r16 TLP). No LDS handoff, no extra sync.
__global__ __launch_bounds__(TPB) void vq_finalize(const float* __restrict__ z,
                                                   const float* __restrict__ emb,
                                                   const float* __restrict__ cmin,
                                                   const int* __restrict__ cidx,
                                                   float* __restrict__ out,
                                                   float* __restrict__ ws) {
    const int h = threadIdx.x >> 7;             // channel half 0/1
    const int q = threadIdx.x & 127;
    const int p = blockIdx.x * FPPB + q;        // 64 consecutive px per wave

    // chunk-reduce, duplicated in both halves (8 cheap loads + 8 compares);
    // ascending strict < keeps the earliest (lowest-k) minimum — r16 order.
    const float4* cmv = (const float4*)(cmin + ((size_t)p << 3));
    const int4*   civ = (const int4*)(cidx + ((size_t)p << 3));
    float4 cm0 = cmv[0], cm1 = cmv[1];
    int4   ci0 = civ[0], ci1 = civ[1];
    float best = cm0.x;  int bi = ci0.x;
    if (cm0.y < best) { best = cm0.y; bi = ci0.y; }
    if (cm0.z < best) { best = cm0.z; bi = ci0.z; }
    if (cm0.w < best) { best = cm0.w; bi = ci0.w; }
    if (cm1.x < best) { best = cm1.x; bi = ci1.x; }
    if (cm1.y < best) { best = cm1.y; bi = ci1.y; }
    if (cm1.z < best) { best = cm1.z; bi = ci1.z; }
    if (cm1.w < best) { best = cm1.w; bi = ci1.w; }

    if (h == 0) out[OUT_IDX + p] = (float)bi;   // full 256B per wave0/1

    // this half's 32 channels of the winning row: 8 float4 (bi-scattered,
    // 256KB table -> L1/L2 hits)
    float e[32];
    {
        const float4* ev = (const float4*)(emb + (size_t)bi * CDIM + (h << 5));
#pragma unroll
        for (int j = 0; j < 8; ++j) {
            float4 v = ev[j];
            e[4*j+0] = v.x; e[4*j+1] = v.y; e[4*j+2] = v.z; e[4*j+3] = v.w;
        }
    }

    const int b  = p >> 12;
    const int hw = p & (HWSZ - 1);
    const int c0 = h << 5;                      // 0 or 32
    const float* zp = z   + ((size_t)(b * CDIM + c0) << 12) + hw;
    float*       zq = out + ((size_t)(b * CDIM + c0) << 12) + hw;

    float ls = 0.0f;
#pragma unroll
    for (int j = 0; j < 32; ++j) {
        float zv = zp[(size_t)j << 12];         // ONE 256B segment per wave
        float d = e[j] - zv;                    // identical per-element math
        ls = fmaf(d, d, ls);
        zq[(size_t)j << 12] = e[j];             // ONE 256B segment per wave
    }

    // wave reduce -> 4 block partials -> one atomic; last block emits loss.
    // 32-ch chains + mixed-(px,half) wave grouping: r20 bit-validated.
#pragma unroll
    for (int off = 32; off > 0; off >>= 1) ls += __shfl_down(ls, off);
    __shared__ float wsum[TPB / 64];
    if ((threadIdx.x & 63) == 0) wsum[threadIdx.x >> 6] = ls;
    __syncthreads();
    if (threadIdx.x == 0) {
        float s = (wsum[0] + wsum[1]) + (wsum[2] + wsum[3]);
        float* loss_acc = ws + OFF_LOSS;
        atomicAdd(loss_acc, s);
        __threadfence();                               // add visible before count
        unsigned* ctr = (unsigned*)ws + OFF_CTR;
        unsigned old = atomicAdd(ctr, 1u);
        if (old == (unsigned)(gridDim.x - 1)) {        // last block: all adds done
            __threadfence();
            float total = atomicAdd(loss_acc, 0.0f);   // coherent L2 read
            // vq_loss + beta*commitment = (1+0.25) * SSE / numel(z)
            out[OUT_LOSS] = total * (1.25f / (float)(N_PIX * CDIM));
        }
    }
}

extern "C" void kernel_launch(void* const* d_in, const int* in_sizes, int n_in,
                              void* d_out, int out_size, void* d_ws, size_t ws_size,
                              hipStream_t stream) {
    const float* z   = (const float*)d_in[0];
    const float* emb = (const float*)d_in[1];
    float* ws   = (float*)d_ws;
    float* out  = (float*)d_out;
    float* cmin = ws + OFF_MIN;
    int*   cidx = (int*)(ws + OFF_IDX);

    vq_argmin<<<dim3(GRIDX, NCHUNK), dim3(TPB), 0, stream>>>(z, emb, cmin, cidx, ws);
    vq_finalize<<<dim3(N_PIX / FPPB), dim3(TPB), 0, stream>>>(z, emb, cmin, cidx, out, ws);
}

// Round 14
// 195.812 us; speedup vs baseline: 1.4382x; 1.0692x over previous
//
#include <hip/hip_runtime.h>

// VQ-VAE vector quantization, MI355X gfx950. FINAL (r24 = r16 verbatim;
// r23 submission identical, bench was an infra failure — resubmitted).
// B=16, C=64, H=W=64 -> N=65536 pixels; K=1024 codes, dim 64.
// NUMERICS (DO NOT CHANGE — r7 passed absmax 0.0 with exactly this):
//   nz/ne: numpy pairwise sum, 8-accumulator unroll, products rounded
//          separately (no fma contraction);
//   dot:   single ascending fp32 fma chain per (pixel,code);
//   d = fl( fl(nz - fl(2*dot)) + ne ); strict-< ascending-k tie-break.
//   ~135 pixels are decided by quantized ties.
//
// Session conclusion (13 rounds, 13 structural variants):
//   argmin (8 variants): floor ~133 µs. The bit-exactness lock forces a
//     serial ascending fp32 fma chain per (pixel,code) -> pure VALU floor
//     ~100 µs (103 TF m07 scalar-FMA ceiling, no fp32-input MFMA on CDNA4);
//     residual ~30% is operand delivery, attacked via LDS-broadcast (r9),
//     SGPR-stream (r15), hybrid (r16), rebalance (r19): <=2% spread.
//   finalize (6 forms): r16's 1-px/thread form beats ALL restructures
//     (r17 FB=128: +8; r18 4-way split: +15; r20 half-wave split: +8;
//     r21 atomic fusion: +86; r22 wave-aligned 2x TLP: +13). Its long
//     per-thread streams + block-local emb L1 reuse + zero duplication
//     beat every TLP-raising alternative.
//   Best measured: THIS KERNEL, 196.27 µs (round 6 bench).
//
// Perf history:
//   r7 161 | r8 185 | r9 137 | r12 242 | r13 137 | r14 1244 | r15 135
//   r16 hybrid LDS+SGPR argmin 133, total 196 (BEST — this file).
//   r17 209 | r18 218 | r19 201 | r20 204 | r21 282 | r22 209 | r23 infra.
#define N_PIX   65536
#define CDIM    64
#define KCODES  1024
#define HWSZ    4096          // H*W
#define KCHUNK  128           // codes per argmin block
#define NCHUNK  8             // KCODES / KCHUNK
#define TPB     256
#define PXT     2             // pixels per thread; 128*256*2 == N_PIX exactly
#define GRIDX   (N_PIX / (TPB * PXT))   // 128

// workspace layout (float-element offsets)
#define OFF_CTR  0            // 1 u32: finalize done-counter
#define OFF_MIN  1024         // 65536*8 f32: per-chunk min score
#define OFF_IDX  525312       // 65536*8 i32: per-chunk argmin
#define OFF_LOSS 1049600      // 1 f32: SSE accumulator

// output layout (float-element offsets): z_q | indices | loss
#define OUT_IDX  (N_PIX * CDIM)         // 4194304
#define OUT_LOSS (OUT_IDX + N_PIX)      // 4259840

typedef __attribute__((ext_vector_type(16))) float f32x16;

// exact numpy pairwise ||.||^2 for pixel registers — EXACT r9-verified form.
__device__ __forceinline__ float np_nz(const float* zr) {
    float r0 = zr[0]*zr[0], r1 = zr[1]*zr[1], r2 = zr[2]*zr[2], r3 = zr[3]*zr[3];
    float r4 = zr[4]*zr[4], r5 = zr[5]*zr[5], r6 = zr[6]*zr[6], r7 = zr[7]*zr[7];
#pragma unroll
    for (int i = 8; i < CDIM; i += 8) {
        r0 = r0 + zr[i+0]*zr[i+0]; r1 = r1 + zr[i+1]*zr[i+1];
        r2 = r2 + zr[i+2]*zr[i+2]; r3 = r3 + zr[i+3]*zr[i+3];
        r4 = r4 + zr[i+4]*zr[i+4]; r5 = r5 + zr[i+5]*zr[i+5];
        r6 = r6 + zr[i+6]*zr[i+6]; r7 = r7 + zr[i+7]*zr[i+7];
    }
    return ((r0 + r1) + (r2 + r3)) + ((r4 + r5) + (r6 + r7));
}

// ---------------- Kernel A: split-K argmin, hybrid LDS+SGPR operands --------
// grid = (GRIDX, NCHUNK); block = TPB.
__global__ __launch_bounds__(TPB, 3) void vq_argmin(const float* __restrict__ z,
                                                    const float* __restrict__ emb,
                                                    float* __restrict__ cmin,
                                                    int* __restrict__ cidx,
                                                    float* __restrict__ ws) {
#pragma clang fp contract(off)
    __shared__ float se[KCHUNK * CDIM];   // 32 KB
    __shared__ float sn[KCHUNK];

    const int chunk = blockIdx.y;
    const int k0 = chunk * KCHUNK;

    if ((blockIdx.x | blockIdx.y) == 0 && threadIdx.x == 0) {
        ws[OFF_LOSS] = 0.0f;                       // stream-ordered before finalize
        ((unsigned*)ws)[OFF_CTR] = 0u;             // graph-replay / re-poison safe
    }

    // stage this chunk's embedding rows (coalesced float4)
    const float4* esrc = (const float4*)(emb + (size_t)k0 * CDIM);
    float4* edst = (float4*)se;
    for (int i = threadIdx.x; i < KCHUNK * CDIM / 4; i += TPB) edst[i] = esrc[i];
    __syncthreads();
    // fused prep: ||e_k||^2 from the bit-exact staged copy (validated r12-r16).
    // Known cost: 32-way bank conflict here, ~2M cycles (~3 µs). Accepted.
    if (threadIdx.x < KCHUNK) {
        const float* e = se + threadIdx.x * CDIM;
        float r0 = e[0]*e[0], r1 = e[1]*e[1], r2 = e[2]*e[2], r3 = e[3]*e[3];
        float r4 = e[4]*e[4], r5 = e[5]*e[5], r6 = e[6]*e[6], r7 = e[7]*e[7];
#pragma unroll
        for (int i = 8; i < CDIM; i += 8) {
            r0 = r0 + e[i+0]*e[i+0]; r1 = r1 + e[i+1]*e[i+1];
            r2 = r2 + e[i+2]*e[i+2]; r3 = r3 + e[i+3]*e[i+3];
            r4 = r4 + e[i+4]*e[i+4]; r5 = r5 + e[i+5]*e[i+5];
            r6 = r6 + e[i+6]*e[i+6]; r7 = r7 + e[i+7]*e[i+7];
        }
        sn[threadIdx.x] = ((r0 + r1) + (r2 + r3)) + ((r4 + r5) + (r6 + r7));
    }
    __syncthreads();

    // two pixels per thread, lane-coalesced; no tail (128*256*2 == N_PIX)
    const int p0 = blockIdx.x * (TPB * PXT) + threadIdx.x;
    const int p1 = p0 + TPB;

    float zr0[CDIM], zr1[CDIM];
    {
        const int b0  = p0 >> 12, hw0 = p0 & (HWSZ - 1);
        const int b1  = p1 >> 12, hw1 = p1 & (HWSZ - 1);
        const float* zp0 = z + ((size_t)(b0 * CDIM) << 12) + hw0;
        const float* zp1 = z + ((size_t)(b1 * CDIM) << 12) + hw1;
#pragma unroll
        for (int c = 0; c < CDIM; ++c) {
            zr0[c] = zp0[(size_t)c << 12];
            zr1[c] = zp1[(size_t)c << 12];
        }
    }
    const float nz0 = np_nz(zr0);
    const float nz1 = np_nz(zr1);

    float best0 = 3.4e38f, best1 = 3.4e38f;
    int   bi0   = k0,      bi1   = k0;

    for (int kk = 0; kk < KCHUNK; kk += 2) {
        // --- issue SGPR stream for code kk+1 (erow + 0x100..0x1c0) ---------
        const float* erow = emb + (size_t)(k0 + kk) * CDIM;
        f32x16 ec0, ec1, ec2, ec3;
        asm volatile(
            "s_load_dwordx16 %0, %4, 0x100\n\t"
            "s_load_dwordx16 %1, %4, 0x140\n\t"
            "s_load_dwordx16 %2, %4, 0x180\n\t"
            "s_load_dwordx16 %3, %4, 0x1c0"
            : "=s"(ec0), "=s"(ec1), "=s"(ec2), "=s"(ec3)
            : "s"(erow));

        // --- LDS phase: code kk for both pixels (r9's exact chains) --------
        const float4* e0 = (const float4*)(se + kk * CDIM);
        float a00 = 0.f, a01 = 0.f, a10 = 0.f, a11 = 0.f;
#pragma unroll
        for (int j = 0; j < 16; ++j) {
            float4 v0 = e0[j];                 // uniform addr -> LDS broadcast
            a00 = fmaf(zr0[4*j+0], v0.x, a00);
            a00 = fmaf(zr0[4*j+1], v0.y, a00);
            a00 = fmaf(zr0[4*j+2], v0.z, a00);
            a00 = fmaf(zr0[4*j+3], v0.w, a00);
            a10 = fmaf(zr1[4*j+0], v0.x, a10);
            a10 = fmaf(zr1[4*j+1], v0.y, a10);
            a10 = fmaf(zr1[4*j+2], v0.z, a10);
            a10 = fmaf(zr1[4*j+3], v0.w, a10);
        }

        // --- wait: pinned AFTER the LDS phase (produces a00,a10) and BEFORE
        //     the SGPR phase (consumes ec0..ec3 as this asm's outputs) -------
        asm volatile("s_waitcnt lgkmcnt(0)"
                     : "+s"(ec0), "+s"(ec1), "+s"(ec2), "+s"(ec3),
                       "+v"(a00), "+v"(a10));

        // --- SGPR phase: code kk+1 for both pixels (r15's exact chains) ----
#pragma unroll
        for (int j = 0; j < 16; ++j) {
            a01 = fmaf(zr0[j], ec0[j], a01);   // v_fma: VGPR,SGPR,VGPR
            a11 = fmaf(zr1[j], ec0[j], a11);
        }
#pragma unroll
        for (int j = 0; j < 16; ++j) {
            a01 = fmaf(zr0[16+j], ec1[j], a01);
            a11 = fmaf(zr1[16+j], ec1[j], a11);
        }
#pragma unroll
        for (int j = 0; j < 16; ++j) {
            a01 = fmaf(zr0[32+j], ec2[j], a01);
            a11 = fmaf(zr1[32+j], ec2[j], a11);
        }
#pragma unroll
        for (int j = 0; j < 16; ++j) {
            a01 = fmaf(zr0[48+j], ec3[j], a01);
            a11 = fmaf(zr1[48+j], ec3[j], a11);
        }

        // d and argmin — exact r9 expression shapes and update order
        float d00 = (nz0 - 2.0f * a00) + sn[kk];
        float d01 = (nz0 - 2.0f * a01) + sn[kk + 1];
        float d10 = (nz1 - 2.0f * a10) + sn[kk];
        float d11 = (nz1 - 2.0f * a11) + sn[kk + 1];
        if (d00 < best0) { best0 = d00; bi0 = k0 + kk; }
        if (d01 < best0) { best0 = d01; bi0 = k0 + kk + 1; }
        if (d10 < best1) { best1 = d10; bi1 = k0 + kk; }
        if (d11 < best1) { best1 = d11; bi1 = k0 + kk + 1; }
    }
    cmin[(p0 << 3) + chunk] = best0;
    cidx[(p0 << 3) + chunk] = bi0;
    cmin[(p1 << 3) + chunk] = best1;
    cidx[(p1 << 3) + chunk] = bi1;
}

// ---------------- Kernel B: reduce chunks, gather z_q, loss + emit ----------
// 1 thread = 1 pixel, full 64-channel loop. Empirically optimal among 6
// tested forms: long per-thread streams, block-local emb L1 reuse, zero
// duplicated work. Do not restructure (r17/r18/r20/r21/r22 all regressed).
__global__ __launch_bounds__(TPB) void vq_finalize(const float* __restrict__ z,
                                                   const float* __restrict__ emb,
                                                   const float* __restrict__ cmin,
                                                   const int* __restrict__ cidx,
                                                   float* __restrict__ out,
                                                   float* __restrict__ ws) {
    const int p = blockIdx.x * TPB + threadIdx.x;

    // ascending-chunk strict < keeps the earliest (lowest-k) minimum
    float best = cmin[p << 3];
    int   bi   = cidx[p << 3];
#pragma unroll
    for (int ch = 1; ch < NCHUNK; ++ch) {
        float m = cmin[(p << 3) + ch];
        if (m < best) { best = m; bi = cidx[(p << 3) + ch]; }
    }

    out[OUT_IDX + p] = (float)bi;       // indices output (fp32)

    const float* ev = emb + bi * CDIM;
    const int b  = p >> 12;
    const int hw = p & (HWSZ - 1);
    const float* zp = z + ((size_t)(b * CDIM) << 12) + hw;
    float* zq = out + ((size_t)(b * CDIM) << 12) + hw;

    float ls = 0.0f;
#pragma unroll
    for (int c = 0; c < CDIM; ++c) {
        float e = ev[c];                    // gather: rows hit L1/L2 (256KB table)
        float zv = zp[(size_t)c << 12];
        float d = e - zv;
        ls = fmaf(d, d, ls);
        zq[(size_t)c << 12] = e;            // fp32 z_q, coalesced strided store
    }

    // block reduction -> one atomic per block; last block scales + emits loss
#pragma unroll
    for (int off = 32; off > 0; off >>= 1) ls += __shfl_down(ls, off);
    __shared__ float wsum[TPB / 64];
    if ((threadIdx.x & 63) == 0) wsum[threadIdx.x >> 6] = ls;
    __syncthreads();
    if (threadIdx.x == 0) {
        float s = wsum[0] + wsum[1] + wsum[2] + wsum[3];
        float* loss_acc = ws + OFF_LOSS;
        atomicAdd(loss_acc, s);
        __threadfence();                               // add visible before count
        unsigned* ctr = (unsigned*)ws + OFF_CTR;
        unsigned old = atomicAdd(ctr, 1u);
        if (old == (unsigned)(gridDim.x - 1)) {        // last block: all adds done
            __threadfence();
            float total = atomicAdd(loss_acc, 0.0f);   // coherent L2 read
            // vq_loss + beta*commitment = (1+0.25) * SSE / numel(z)
            out[OUT_LOSS] = total * (1.25f / (float)(N_PIX * CDIM));
        }
    }
}

extern "C" void kernel_launch(void* const* d_in, const int* in_sizes, int n_in,
                              void* d_out, int out_size, void* d_ws, size_t ws_size,
                              hipStream_t stream) {
    const float* z   = (const float*)d_in[0];
    const float* emb = (const float*)d_in[1];
    float* ws   = (float*)d_ws;
    float* out  = (float*)d_out;
    float* cmin = ws + OFF_MIN;
    int*   cidx = (int*)(ws + OFF_IDX);

    vq_argmin<<<dim3(GRIDX, NCHUNK), dim3(TPB), 0, stream>>>(z, emb, cmin, cidx, ws);
    vq_finalize<<<dim3(N_PIX / TPB), dim3(TPB), 0, stream>>>(z, emb, cmin, cidx, out, ws);
}